// Round 11
// baseline (60.335 us; speedup 1.0000x reference)
//
#include <hip/hip_runtime.h>

#define GG 1000
#define NPG 500
#define KK 8
#define N1 128
#define N2 128
#define NEG_SLOPE 0.45f
#define NTHREADS 256
#define NWAVES 4
#define NVW 8                      // virtual waves of 64 nodes in the sort
#define CHUNKW 125                 // sorted entries per wave (4 x 125 = 500)

typedef float fx2 __attribute__((ext_vector_type(2)));

__global__ __launch_bounds__(NTHREADS, 8) void cluster_attn_kernel(
    const float* __restrict__ x,
    const float* __restrict__ W1,
    const float* __restrict__ b1,
    const float* __restrict__ Wa,
    const float* __restrict__ ba,
    const int*   __restrict__ cls,
    float*       __restrict__ out)
{
    __shared__ float s_acc[KK][N1];
    __shared__ int   s_cls[NPG];
    __shared__ int   s_order[NPG];
    __shared__ int   s_wcnt[NVW][KK];
    __shared__ int   s_start[KK];
    __shared__ float s_Lp[NVW][KK];    // 8 partial-logit slots (wave, tile)
    __shared__ float s_fcnt[KK];
    __shared__ float s_ratio[KK];
    __shared__ float s_e[KK];

    const int g   = blockIdx.x;
    const int tid = threadIdx.x;
    const int w   = tid >> 6;          // wave 0..3
    const int l   = tid & 63;

    const int* clsg = cls + (size_t)g * NPG;
    float* accf = &s_acc[0][0];
    for (int i = tid; i < KK * N1; i += NTHREADS) accf[i] = 0.f;

    // ---- 2-round ballot sort: virtual wave vw = 2w+r owns nodes [64vw,64vw+64)
    int myc[2];
    unsigned long long mymask[2];
    #pragma unroll
    for (int r = 0; r < 2; ++r) {
        const int node = ((w << 1) + r) << 6 | l;
        int c = -1;
        if (node < NPG) { c = clsg[node]; s_cls[node] = c; }
        myc[r] = c; mymask[r] = 0;
        #pragma unroll
        for (int k = 0; k < KK; ++k) {
            unsigned long long m = __ballot(c == k);
            if (l == 0) s_wcnt[(w << 1) + r][k] = (int)__popcll(m);
            if (c == k) mymask[r] = m;
        }
    }
    __syncthreads();

    if (tid == 0) {                    // totals, bucket starts, ratios
        int run = 0; float d = 0.f;
        #pragma unroll
        for (int k = 0; k < KK; ++k) {
            int t = 0;
            #pragma unroll
            for (int vv = 0; vv < NVW; ++vv) t += s_wcnt[vv][k];
            s_start[k] = run; run += t;
            float c = (float)t; s_fcnt[k] = c; d += c * c;
        }
        #pragma unroll
        for (int k = 0; k < KK; ++k) s_ratio[k] = s_fcnt[k] / d;
    }
    __syncthreads();

    #pragma unroll
    for (int r = 0; r < 2; ++r) {      // deterministic collision-free scatter
        const int node = ((w << 1) + r) << 6 | l;
        if (node < NPG) {
            const int vw = (w << 1) + r;
            int before = 0;
            for (int vv = 0; vv < vw; ++vv) before += s_wcnt[vv][myc[r]];
            before += (int)__popcll(mymask[r] & ((1ULL << l) - 1ULL));
            s_order[s_start[myc[r]] + before] = node | (myc[r] << 12);
        }
    }
    __syncthreads();

    // ---- phase 1: wave walks its 125 sorted entries; register-run accumulate ----
    const fx2* x2 = (const fx2*)(x + (size_t)g * NPG * N1);
    {
        const int begin = w * CHUNKW;
        const int end   = begin + CHUNKW;
        int cur = __builtin_amdgcn_readfirstlane(s_order[begin]) >> 12;
        float a0 = 0.f, a1 = 0.f;
        int e = begin;

#define STEP(P, V)                                                      \
        {                                                               \
            int c_ = (P) >> 12;                                         \
            if (c_ != cur) {            /* wave-uniform, rare */        \
                atomicAdd(&s_acc[cur][2 * l],     a0);                  \
                atomicAdd(&s_acc[cur][2 * l + 1], a1);                  \
                a0 = 0.f; a1 = 0.f; cur = c_;                           \
            }                                                           \
            a0 += (V).x; a1 += (V).y;                                   \
        }

        for (; e + 4 <= end; e += 4) {
            int p0 = __builtin_amdgcn_readfirstlane(s_order[e]);
            int p1 = __builtin_amdgcn_readfirstlane(s_order[e + 1]);
            int p2 = __builtin_amdgcn_readfirstlane(s_order[e + 2]);
            int p3 = __builtin_amdgcn_readfirstlane(s_order[e + 3]);
            fx2 v0 = x2[(size_t)(p0 & 0xFFF) * 64 + l];   // 4x512B in flight
            fx2 v1 = x2[(size_t)(p1 & 0xFFF) * 64 + l];
            fx2 v2 = x2[(size_t)(p2 & 0xFFF) * 64 + l];
            fx2 v3 = x2[(size_t)(p3 & 0xFFF) * 64 + l];
            STEP(p0, v0) STEP(p1, v1) STEP(p2, v2) STEP(p3, v3)
        }
        for (; e < end; ++e) {
            int p = __builtin_amdgcn_readfirstlane(s_order[e]);
            fx2 v = x2[(size_t)(p & 0xFFF) * 64 + l];
            STEP(p, v)
        }
#undef STEP
        atomicAdd(&s_acc[cur][2 * l],     a0);
        atomicAdd(&s_acc[cur][2 * l + 1], a1);
    }
    __syncthreads();

    // ---- phase 2 (W1 read once per block): wave w owns j-tiles 2w, 2w+1 ----
    #pragma unroll
    for (int r = 0; r < 2; ++r) {
        const int   jt  = (w << 5) + (r << 4) + (l & 15);
        const int   fg  = l >> 4;
        const float b1j = b1[jt];
        const float Waj = Wa[jt];
        float p[KK];
        #pragma unroll
        for (int k = 0; k < KK; ++k) p[k] = 0.f;

        const float* w1p = W1 + (size_t)(fg * 32) * N2 + jt;
        #pragma unroll 4
        for (int i = 0; i < 32; ++i) {
            const float wv = w1p[(size_t)i * N2];
            const int   f  = fg * 32 + i;
            #pragma unroll
            for (int k = 0; k < KK; ++k)
                p[k] = fmaf(accf[k * N1 + f], wv, p[k]);
        }
        #pragma unroll
        for (int k = 0; k < KK; ++k) {
            float v = p[k];
            v += __shfl_xor(v, 16);
            v += __shfl_xor(v, 32);
            float val = fmaf(v, s_ratio[k], b1j);
            float h = val > 0.f ? val : NEG_SLOPE * val;
            float c = h * Waj;
            c += __shfl_xor(c, 1);
            c += __shfl_xor(c, 2);
            c += __shfl_xor(c, 4);
            c += __shfl_xor(c, 8);
            if (l == 0) s_Lp[(w << 1) + r][k] = c;
        }
    }
    __syncthreads();

    // ---- phase 3: logits -> count-weighted softmax ----
    if (tid == 0) {
        float Lk[KK];
        #pragma unroll
        for (int k = 0; k < KK; ++k) {
            float s = ba[0];
            #pragma unroll
            for (int vv = 0; vv < NVW; ++vv) s += s_Lp[vv][k];
            Lk[k] = s;
        }
        float m = -1e30f;
        #pragma unroll
        for (int k = 0; k < KK; ++k)
            if (s_fcnt[k] > 0.f) m = fmaxf(m, Lk[k]);
        float ssum = 0.f;
        float ek[KK];
        #pragma unroll
        for (int k = 0; k < KK; ++k) {
            ek[k] = (s_fcnt[k] > 0.f) ? expf(Lk[k] - m) : 0.f;
            ssum += s_fcnt[k] * ek[k];
        }
        #pragma unroll
        for (int k = 0; k < KK; ++k) s_e[k] = ek[k] / ssum;
    }
    __syncthreads();

    // ---- phase 4: per-node output = table lookup ----
    float* outg = out + (size_t)g * NPG;
    for (int n = tid; n < NPG; n += NTHREADS) outg[n] = s_e[s_cls[n]];
}

extern "C" void kernel_launch(void* const* d_in, const int* in_sizes, int n_in,
                              void* d_out, int out_size, void* d_ws, size_t ws_size,
                              hipStream_t stream) {
    const float* x   = (const float*)d_in[0];
    const float* W1  = (const float*)d_in[1];
    const float* b1  = (const float*)d_in[2];
    const float* Wa  = (const float*)d_in[3];
    const float* ba  = (const float*)d_in[4];
    const int*   cls = (const int*)d_in[5];

    float* out = (float*)d_out;
    cluster_attn_kernel<<<GG, NTHREADS, 0, stream>>>(x, W1, b1, Wa, ba, cls, out);
}

// Round 12
// 51.522 us; speedup vs baseline: 1.1710x; 1.1710x over previous
//
#include <hip/hip_runtime.h>

#define GG 1000
#define NPG 500
#define KK 8
#define N1 128
#define N2 128
#define NEG_SLOPE 0.45f
#define NTHREADS 512
#define NWAVES 8
#define CHUNK ((NPG + NWAVES - 1) / NWAVES)   // 63

typedef float fx2 __attribute__((ext_vector_type(2)));

__global__ __launch_bounds__(NTHREADS) void cluster_attn_kernel(
    const float* __restrict__ x,
    const float* __restrict__ W1,
    const float* __restrict__ b1,
    const float* __restrict__ Wa,
    const float* __restrict__ ba,
    const int*   __restrict__ cls,
    float*       __restrict__ out)
{
    __shared__ float s_acc[KK][N1];
    __shared__ int   s_cls[NPG];
    __shared__ int   s_order[NPG];
    __shared__ int   s_wcnt[NWAVES][KK];
    __shared__ int   s_start[KK];
    __shared__ float s_Lp[NWAVES][KK];
    __shared__ float s_fcnt[KK];
    __shared__ float s_ratio[KK];
    __shared__ float s_e[KK];

    const int g   = blockIdx.x;
    const int tid = threadIdx.x;
    const int w   = tid >> 6;
    const int l   = tid & 63;

    const int* clsg = cls + (size_t)g * NPG;
    float* accf = &s_acc[0][0];
    for (int i = tid; i < KK * N1; i += NTHREADS) accf[i] = 0.f;

    int myc = -1;
    if (tid < NPG) { myc = clsg[tid]; s_cls[tid] = myc; }

    // ---- deterministic bucket ranks via wave ballots (no atomics) ----
    unsigned long long mymask = 0;
    #pragma unroll
    for (int k = 0; k < KK; ++k) {
        unsigned long long m = __ballot(myc == k);
        if (l == 0) s_wcnt[w][k] = (int)__popcll(m);
        if (myc == k) mymask = m;
    }
    __syncthreads();

    if (tid == 0) {
        int run = 0; float d = 0.f;
        #pragma unroll
        for (int k = 0; k < KK; ++k) {
            int t = 0;
            #pragma unroll
            for (int ww = 0; ww < NWAVES; ++ww) t += s_wcnt[ww][k];
            s_start[k] = run; run += t;
            float c = (float)t; s_fcnt[k] = c; d += c * c;
        }
        #pragma unroll
        for (int k = 0; k < KK; ++k) s_ratio[k] = s_fcnt[k] / d;
    }
    __syncthreads();

    if (tid < NPG) {
        int before = 0;
        for (int ww = 0; ww < w; ++ww) before += s_wcnt[ww][myc];
        before += (int)__popcll(mymask & ((1ULL << l) - 1ULL));
        s_order[s_start[myc] + before] = tid | (myc << 12);
    }
    __syncthreads();

    // ---- phase 1: sorted run-walk, SOFTWARE-PIPELINED loads.
    //      Triple-buffered groups of 4: issue group i's loads BEFORE the
    //      branchy STEPs of group i-2 -> 8 loads in flight per wave.      ----
    const fx2* x2 = (const fx2*)(x + (size_t)g * NPG * N1);
    {
        const int begin = w * CHUNK;
        int end = begin + CHUNK; if (end > NPG) end = NPG;
        if (begin < end) {
            int cur = __builtin_amdgcn_readfirstlane(s_order[begin]) >> 12;
            float a0 = 0.f, a1 = 0.f;

#define RF(I) __builtin_amdgcn_readfirstlane(s_order[(I)])
#define LOADG(P0,P1,P2,P3,V0,V1,V2,V3,BASE)                               \
            P0 = RF((BASE));     P1 = RF((BASE) + 1);                     \
            P2 = RF((BASE) + 2); P3 = RF((BASE) + 3);                     \
            V0 = x2[(size_t)(P0 & 0xFFF) * 64 + l];                       \
            V1 = x2[(size_t)(P1 & 0xFFF) * 64 + l];                       \
            V2 = x2[(size_t)(P2 & 0xFFF) * 64 + l];                       \
            V3 = x2[(size_t)(P3 & 0xFFF) * 64 + l];
#define STEP(P, V)                                                        \
            {                                                             \
                int c_ = (P) >> 12;                                       \
                if (c_ != cur) {            /* wave-uniform, rare */      \
                    atomicAdd(&s_acc[cur][2 * l],     a0);                \
                    atomicAdd(&s_acc[cur][2 * l + 1], a1);                \
                    a0 = 0.f; a1 = 0.f; cur = c_;                         \
                }                                                         \
                a0 += (V).x; a1 += (V).y;                                 \
            }
#define STEP4(P0,P1,P2,P3,V0,V1,V2,V3) STEP(P0,V0) STEP(P1,V1) STEP(P2,V2) STEP(P3,V3)

            const int ng = (end - begin) >> 2;    // full groups of 4 (>=14 here)
            int e;
            if (ng >= 2) {
                int pa0,pa1,pa2,pa3, pb0,pb1,pb2,pb3, pc0,pc1,pc2,pc3;
                fx2 va0,va1,va2,va3, vb0,vb1,vb2,vb3, vc0,vc1,vc2,vc3;
                LOADG(pa0,pa1,pa2,pa3, va0,va1,va2,va3, begin)
                LOADG(pb0,pb1,pb2,pb3, vb0,vb1,vb2,vb3, begin + 4)
                for (int i = 2; i < ng; ++i) {
                    LOADG(pc0,pc1,pc2,pc3, vc0,vc1,vc2,vc3, begin + (i << 2))
                    STEP4(pa0,pa1,pa2,pa3, va0,va1,va2,va3)
                    pa0=pb0; pa1=pb1; pa2=pb2; pa3=pb3;
                    va0=vb0; va1=vb1; va2=vb2; va3=vb3;
                    pb0=pc0; pb1=pc1; pb2=pc2; pb3=pc3;
                    vb0=vc0; vb1=vc1; vb2=vc2; vb3=vc3;
                }
                STEP4(pa0,pa1,pa2,pa3, va0,va1,va2,va3)
                STEP4(pb0,pb1,pb2,pb3, vb0,vb1,vb2,vb3)
                e = begin + (ng << 2);
            } else {
                e = begin;
            }
            for (; e < end; ++e) {                 // tail (<=3 entries)
                int p = RF(e);
                fx2 v = x2[(size_t)(p & 0xFFF) * 64 + l];
                STEP(p, v)
            }
            atomicAdd(&s_acc[cur][2 * l],     a0); // final run flush
            atomicAdd(&s_acc[cur][2 * l + 1], a1);
#undef STEP4
#undef STEP
#undef LOADG
#undef RF
        }
    }
    __syncthreads();

    // ---- phase 2 (W1 read once per block): wave w owns j-tile [16w,16w+16) ----
    {
        const int   jt  = (w << 4) + (l & 15);
        const int   fg  = l >> 4;
        const float b1j = b1[jt];
        const float Waj = Wa[jt];
        float p[KK];
        #pragma unroll
        for (int k = 0; k < KK; ++k) p[k] = 0.f;

        const float* w1p = W1 + (size_t)(fg * 32) * N2 + jt;
        #pragma unroll 4
        for (int i = 0; i < 32; ++i) {
            const float wv = w1p[(size_t)i * N2];
            const int   f  = fg * 32 + i;
            #pragma unroll
            for (int k = 0; k < KK; ++k)
                p[k] = fmaf(accf[k * N1 + f], wv, p[k]);
        }
        #pragma unroll
        for (int k = 0; k < KK; ++k) {
            float v = p[k];
            v += __shfl_xor(v, 16);
            v += __shfl_xor(v, 32);
            float val = fmaf(v, s_ratio[k], b1j);
            float h = val > 0.f ? val : NEG_SLOPE * val;
            float c = h * Waj;
            c += __shfl_xor(c, 1);
            c += __shfl_xor(c, 2);
            c += __shfl_xor(c, 4);
            c += __shfl_xor(c, 8);
            if (l == 0) s_Lp[w][k] = c;
        }
    }
    __syncthreads();

    // ---- phase 3: logits -> count-weighted softmax ----
    if (tid == 0) {
        float Lk[KK];
        #pragma unroll
        for (int k = 0; k < KK; ++k) {
            float s = ba[0];
            #pragma unroll
            for (int ww = 0; ww < NWAVES; ++ww) s += s_Lp[ww][k];
            Lk[k] = s;
        }
        float m = -1e30f;
        #pragma unroll
        for (int k = 0; k < KK; ++k)
            if (s_fcnt[k] > 0.f) m = fmaxf(m, Lk[k]);
        float ssum = 0.f;
        float ek[KK];
        #pragma unroll
        for (int k = 0; k < KK; ++k) {
            ek[k] = (s_fcnt[k] > 0.f) ? expf(Lk[k] - m) : 0.f;
            ssum += s_fcnt[k] * ek[k];
        }
        #pragma unroll
        for (int k = 0; k < KK; ++k) s_e[k] = ek[k] / ssum;
    }
    __syncthreads();

    // ---- phase 4: per-node output = table lookup ----
    float* outg = out + (size_t)g * NPG;
    for (int n = tid; n < NPG; n += NTHREADS) outg[n] = s_e[s_cls[n]];
}

extern "C" void kernel_launch(void* const* d_in, const int* in_sizes, int n_in,
                              void* d_out, int out_size, void* d_ws, size_t ws_size,
                              hipStream_t stream) {
    const float* x   = (const float*)d_in[0];
    const float* W1  = (const float*)d_in[1];
    const float* b1  = (const float*)d_in[2];
    const float* Wa  = (const float*)d_in[3];
    const float* ba  = (const float*)d_in[4];
    const int*   cls = (const int*)d_in[5];

    float* out = (float*)d_out;
    cluster_attn_kernel<<<GG, NTHREADS, 0, stream>>>(x, W1, b1, Wa, ba, cls, out);
}

// Round 13
// 51.118 us; speedup vs baseline: 1.1803x; 1.0079x over previous
//
#include <hip/hip_runtime.h>

#define GG 1000
#define NPG 500
#define KK 8
#define N1 128
#define N2 128
#define NEG_SLOPE 0.45f
#define NTHREADS 512
#define NWAVES 8
#define CHUNK ((NPG + NWAVES - 1) / NWAVES)   // 63 <= 64: chunk fits in one VGPR

typedef float fx2 __attribute__((ext_vector_type(2)));

__global__ __launch_bounds__(NTHREADS) void cluster_attn_kernel(
    const float* __restrict__ x,
    const float* __restrict__ W1,
    const float* __restrict__ b1,
    const float* __restrict__ Wa,
    const float* __restrict__ ba,
    const int*   __restrict__ cls,
    float*       __restrict__ out)
{
    __shared__ float s_acc[KK][N1];
    __shared__ int   s_cls[NPG];
    __shared__ int   s_order[NPG];
    __shared__ int   s_wcnt[NWAVES][KK];
    __shared__ int   s_start[KK];
    __shared__ float s_Lp[NWAVES][KK];
    __shared__ float s_fcnt[KK];
    __shared__ float s_ratio[KK];
    __shared__ float s_e[KK];

    const int g   = blockIdx.x;
    const int tid = threadIdx.x;
    const int w   = tid >> 6;
    const int l   = tid & 63;

    const int* clsg = cls + (size_t)g * NPG;
    float* accf = &s_acc[0][0];
    for (int i = tid; i < KK * N1; i += NTHREADS) accf[i] = 0.f;

    int myc = -1;
    if (tid < NPG) { myc = clsg[tid]; s_cls[tid] = myc; }

    // ---- deterministic bucket ranks via wave ballots (no atomics) ----
    unsigned long long mymask = 0;
    #pragma unroll
    for (int k = 0; k < KK; ++k) {
        unsigned long long m = __ballot(myc == k);
        if (l == 0) s_wcnt[w][k] = (int)__popcll(m);
        if (myc == k) mymask = m;
    }
    __syncthreads();

    if (tid == 0) {
        int run = 0; float d = 0.f;
        #pragma unroll
        for (int k = 0; k < KK; ++k) {
            int t = 0;
            #pragma unroll
            for (int ww = 0; ww < NWAVES; ++ww) t += s_wcnt[ww][k];
            s_start[k] = run; run += t;
            float c = (float)t; s_fcnt[k] = c; d += c * c;
        }
        #pragma unroll
        for (int k = 0; k < KK; ++k) s_ratio[k] = s_fcnt[k] / d;
    }
    __syncthreads();

    if (tid < NPG) {
        int before = 0;
        for (int ww = 0; ww < w; ++ww) before += s_wcnt[ww][myc];
        before += (int)__popcll(mymask & ((1ULL << l) - 1ULL));
        s_order[s_start[myc] + before] = tid | (myc << 12);
    }
    __syncthreads();

    // ---- phase 1: REGISTERIZED order (lane i = entry i of this wave's chunk;
    //      readlane -> pure-SGPR address path, no LDS latency), 4-deep
    //      software pipeline: 12 x 512B loads in flight per wave.          ----
    const fx2* x2 = (const fx2*)(x + (size_t)g * NPG * N1);
    {
        const int begin = w * CHUNK;
        int end = begin + CHUNK; if (end > NPG) end = NPG;
        const int len = end - begin;
        int oidx = begin + l; if (oidx > NPG - 1) oidx = NPG - 1;  // pad clamp
        const int ordreg = s_order[oidx];     // one LDS read, then register-only

        int cur = __builtin_amdgcn_readlane(ordreg, 0) >> 12;
        float a0 = 0.f, a1 = 0.f;

#define RL(I) __builtin_amdgcn_readlane(ordreg, (I))
#define LOADG(P0,P1,P2,P3,V0,V1,V2,V3,REL)                                \
            P0 = RL((REL));     P1 = RL((REL) + 1);                       \
            P2 = RL((REL) + 2); P3 = RL((REL) + 3);                       \
            V0 = x2[(size_t)(P0 & 0xFFF) * 64 + l];                       \
            V1 = x2[(size_t)(P1 & 0xFFF) * 64 + l];                       \
            V2 = x2[(size_t)(P2 & 0xFFF) * 64 + l];                       \
            V3 = x2[(size_t)(P3 & 0xFFF) * 64 + l];
#define STEP(P, V)                                                        \
            {                                                             \
                int c_ = (P) >> 12;                                       \
                if (c_ != cur) {            /* wave-uniform, rare */      \
                    atomicAdd(&s_acc[cur][2 * l],     a0);                \
                    atomicAdd(&s_acc[cur][2 * l + 1], a1);                \
                    a0 = 0.f; a1 = 0.f; cur = c_;                         \
                }                                                         \
                a0 += (V).x; a1 += (V).y;                                 \
            }
#define STEP4(P0,P1,P2,P3,V0,V1,V2,V3) STEP(P0,V0) STEP(P1,V1) STEP(P2,V2) STEP(P3,V3)
#define SHIFT(AP0,AP1,AP2,AP3,AV0,AV1,AV2,AV3,BP0,BP1,BP2,BP3,BV0,BV1,BV2,BV3) \
            AP0=BP0; AP1=BP1; AP2=BP2; AP3=BP3;                           \
            AV0=BV0; AV1=BV1; AV2=BV2; AV3=BV3;

        const int ng = len >> 2;              // full groups of 4 (14 or 15)
        int e;
        if (ng >= 3) {
            int pa0,pa1,pa2,pa3, pb0,pb1,pb2,pb3, pc0,pc1,pc2,pc3, pd0,pd1,pd2,pd3;
            fx2 va0,va1,va2,va3, vb0,vb1,vb2,vb3, vc0,vc1,vc2,vc3, vd0,vd1,vd2,vd3;
            LOADG(pa0,pa1,pa2,pa3, va0,va1,va2,va3, 0)
            LOADG(pb0,pb1,pb2,pb3, vb0,vb1,vb2,vb3, 4)
            LOADG(pc0,pc1,pc2,pc3, vc0,vc1,vc2,vc3, 8)
            for (int i = 3; i < ng; ++i) {
                LOADG(pd0,pd1,pd2,pd3, vd0,vd1,vd2,vd3, i << 2)
                STEP4(pa0,pa1,pa2,pa3, va0,va1,va2,va3)
                SHIFT(pa0,pa1,pa2,pa3, va0,va1,va2,va3,
                      pb0,pb1,pb2,pb3, vb0,vb1,vb2,vb3)
                SHIFT(pb0,pb1,pb2,pb3, vb0,vb1,vb2,vb3,
                      pc0,pc1,pc2,pc3, vc0,vc1,vc2,vc3)
                SHIFT(pc0,pc1,pc2,pc3, vc0,vc1,vc2,vc3,
                      pd0,pd1,pd2,pd3, vd0,vd1,vd2,vd3)
            }
            STEP4(pa0,pa1,pa2,pa3, va0,va1,va2,va3)
            STEP4(pb0,pb1,pb2,pb3, vb0,vb1,vb2,vb3)
            STEP4(pc0,pc1,pc2,pc3, vc0,vc1,vc2,vc3)
            e = ng << 2;
        } else {
            e = 0;
        }
        for (; e < len; ++e) {                // tail (<=3 entries)
            int p = RL(e);
            fx2 v = x2[(size_t)(p & 0xFFF) * 64 + l];
            STEP(p, v)
        }
        atomicAdd(&s_acc[cur][2 * l],     a0);
        atomicAdd(&s_acc[cur][2 * l + 1], a1);
#undef SHIFT
#undef STEP4
#undef STEP
#undef LOADG
#undef RL
    }
    __syncthreads();

    // ---- phase 2 (W1 read once per block): wave w owns j-tile [16w,16w+16) ----
    {
        const int   jt  = (w << 4) + (l & 15);
        const int   fg  = l >> 4;
        const float b1j = b1[jt];
        const float Waj = Wa[jt];
        float p[KK];
        #pragma unroll
        for (int k = 0; k < KK; ++k) p[k] = 0.f;

        const float* w1p = W1 + (size_t)(fg * 32) * N2 + jt;
        #pragma unroll 4
        for (int i = 0; i < 32; ++i) {
            const float wv = w1p[(size_t)i * N2];
            const int   f  = fg * 32 + i;
            #pragma unroll
            for (int k = 0; k < KK; ++k)
                p[k] = fmaf(accf[k * N1 + f], wv, p[k]);
        }
        #pragma unroll
        for (int k = 0; k < KK; ++k) {
            float v = p[k];
            v += __shfl_xor(v, 16);
            v += __shfl_xor(v, 32);
            float val = fmaf(v, s_ratio[k], b1j);
            float h = val > 0.f ? val : NEG_SLOPE * val;
            float c = h * Waj;
            c += __shfl_xor(c, 1);
            c += __shfl_xor(c, 2);
            c += __shfl_xor(c, 4);
            c += __shfl_xor(c, 8);
            if (l == 0) s_Lp[w][k] = c;
        }
    }
    __syncthreads();

    // ---- phase 3: logits -> count-weighted softmax ----
    if (tid == 0) {
        float Lk[KK];
        #pragma unroll
        for (int k = 0; k < KK; ++k) {
            float s = ba[0];
            #pragma unroll
            for (int ww = 0; ww < NWAVES; ++ww) s += s_Lp[ww][k];
            Lk[k] = s;
        }
        float m = -1e30f;
        #pragma unroll
        for (int k = 0; k < KK; ++k)
            if (s_fcnt[k] > 0.f) m = fmaxf(m, Lk[k]);
        float ssum = 0.f;
        float ek[KK];
        #pragma unroll
        for (int k = 0; k < KK; ++k) {
            ek[k] = (s_fcnt[k] > 0.f) ? expf(Lk[k] - m) : 0.f;
            ssum += s_fcnt[k] * ek[k];
        }
        #pragma unroll
        for (int k = 0; k < KK; ++k) s_e[k] = ek[k] / ssum;
    }
    __syncthreads();

    // ---- phase 4: per-node output = table lookup ----
    float* outg = out + (size_t)g * NPG;
    for (int n = tid; n < NPG; n += NTHREADS) outg[n] = s_e[s_cls[n]];
}

extern "C" void kernel_launch(void* const* d_in, const int* in_sizes, int n_in,
                              void* d_out, int out_size, void* d_ws, size_t ws_size,
                              hipStream_t stream) {
    const float* x   = (const float*)d_in[0];
    const float* W1  = (const float*)d_in[1];
    const float* b1  = (const float*)d_in[2];
    const float* Wa  = (const float*)d_in[3];
    const float* ba  = (const float*)d_in[4];
    const int*   cls = (const int*)d_in[5];

    float* out = (float*)d_out;
    cluster_attn_kernel<<<GG, NTHREADS, 0, stream>>>(x, W1, b1, Wa, ba, cls, out);
}